// Round 9
// baseline (2583.281 us; speedup 1.0000x reference)
//
#include <hip/hip_runtime.h>
#include <cstdint>

// ---------------------------------------------------------------------------
// GCN forward, single persistent kernel (custom grid barrier, 6 syncs):
//   phase1 hist      : per-block LDS histogram of coarse bucket (dst>>9)
//   phase2 scatter   : fused per-block scan of bhist -> scatter packed edges
//   phase3 fine      : per-bucket 512-bin sort -> srcs CSR (byte offs), meta,
//                      dinv   (256 thr, 2 bins/thread)
//   phase4 gemm1     : MFMA 16x16x32 bf16, x @ W1 -> G16 (*dinv, bf16)
//   phase5 agg+gemm2 : gather layer1 -> H tile in LDS (swizzled) -> MFMA @ W2
//   phase6 agg2      : gather layer2 -> H16 (bf16)
//   phase7 pool+FC   : per-graph mean pool (binary search) + 64x10 FC
// Grid = 1536 blocks x 256 thr = 6 blocks/CU exactly; __launch_bounds__(256,6)
// guarantees co-residency for the barrier. Barrier state zeroed by init_k.
// ---------------------------------------------------------------------------

#define NB_GRID 1536
#define NSORT 256  // blocks participating in hist/scatter phases
#define SCAP 768   // LDS srcs window entries per agg tile (32 nodes, ~384 avg)

typedef __attribute__((ext_vector_type(8))) short bf16x8;
typedef __attribute__((ext_vector_type(4))) float f32x4;

static __device__ __forceinline__ unsigned int f2bf_r(float f) {
    unsigned int u = __float_as_uint(f);
    return u + 0x7FFFu + ((u >> 16) & 1u);  // rounded, needs >>16
}
static __device__ __forceinline__ float bflo(unsigned int v) {
    return __uint_as_float(v << 16);
}
static __device__ __forceinline__ float bfhi(unsigned int v) {
    return __uint_as_float(v & 0xFFFF0000u);
}

__global__ void init_k(unsigned int* bar) {
    if (threadIdx.x < 2) bar[threadIdx.x] = 0u;
}

// sense-reversing grid barrier; bar[0]=count, bar[1]=generation
static __device__ __forceinline__ void gsync(unsigned int* bar) {
    __syncthreads();
    if (threadIdx.x == 0) {
        __threadfence();  // release this block's writes (L2 wb, device scope)
        unsigned int g = __hip_atomic_load(&bar[1], __ATOMIC_RELAXED,
                                           __HIP_MEMORY_SCOPE_AGENT);
        unsigned int a = __hip_atomic_fetch_add(&bar[0], 1u, __ATOMIC_ACQ_REL,
                                                __HIP_MEMORY_SCOPE_AGENT);
        if (a == gridDim.x - 1) {
            __hip_atomic_store(&bar[0], 0u, __ATOMIC_RELEASE,
                               __HIP_MEMORY_SCOPE_AGENT);
            __hip_atomic_fetch_add(&bar[1], 1u, __ATOMIC_ACQ_REL,
                                   __HIP_MEMORY_SCOPE_AGENT);
        } else {
            while (__hip_atomic_load(&bar[1], __ATOMIC_ACQUIRE,
                                     __HIP_MEMORY_SCOPE_AGENT) == g)
                __builtin_amdgcn_s_sleep(2);
        }
        __threadfence();  // acquire: invalidate stale L1/L2 before phase reads
    }
    __syncthreads();
}

__global__ __launch_bounds__(256, 6) void mega_k(
    const int* __restrict__ erow, const int* __restrict__ ecol,
    const float* __restrict__ x, const float* __restrict__ W1,
    const float* __restrict__ b1, const float* __restrict__ W2,
    const float* __restrict__ b2, const float* __restrict__ Wfc,
    const float* __restrict__ bfc, const int* __restrict__ batch,
    unsigned int* __restrict__ bhist, unsigned int* __restrict__ bbase,
    unsigned int* __restrict__ totals, unsigned int* __restrict__ packed,
    uint2* __restrict__ meta, float* __restrict__ dinv,
    unsigned int* __restrict__ srcs, unsigned short* __restrict__ G16,
    unsigned short* __restrict__ G2, unsigned short* __restrict__ H16,
    float* __restrict__ out, unsigned int* __restrict__ bar,
    int N, int E, int Gn, int nbuck, int chunk) {
    __shared__ alignas(16) char smem[7424];
    const int t = threadIdx.x;
    const int blk = blockIdx.x;

    // ---------------- phase 1: coarse histogram ----------------
    if (blk < NSORT) {
        unsigned int* lh = (unsigned int*)smem;
        lh[t] = 0u;
        __syncthreads();
        const int s = blk * chunk;
        const int e = min(s + chunk, E);
        const int n4 = (e - s) >> 2;
        const uint4* ec4 = (const uint4*)(ecol + s);
        for (int i = t; i < n4; i += 256) {
            uint4 v = ec4[i];
            atomicAdd(&lh[v.x >> 9], 1u);
            atomicAdd(&lh[v.y >> 9], 1u);
            atomicAdd(&lh[v.z >> 9], 1u);
            atomicAdd(&lh[v.w >> 9], 1u);
        }
        for (int i = s + (n4 << 2) + t; i < e; i += 256)
            atomicAdd(&lh[((unsigned int)ecol[i]) >> 9], 1u);
        __syncthreads();
        if (t < nbuck) bhist[t * NSORT + blk] = lh[t];
    }
    gsync(bar);

    // ---------------- phase 2: fused scan + scatter ----------------
    if (blk < NSORT) {
        unsigned int* cur = (unsigned int*)smem;
        unsigned int* sc = cur + 256;
        unsigned int total = 0u, mine = 0u;
        if (t < nbuck) {
            const uint4* h4 = (const uint4*)(bhist + t * NSORT);
#pragma unroll 8
            for (int i = 0; i < NSORT / 4; ++i) {
                uint4 v = h4[i];
                const int b0 = i * 4;
                total += v.x + v.y + v.z + v.w;
                mine += (b0 + 0 < blk ? v.x : 0u) + (b0 + 1 < blk ? v.y : 0u) +
                        (b0 + 2 < blk ? v.z : 0u) + (b0 + 3 < blk ? v.w : 0u);
            }
        }
        sc[t] = (t < nbuck) ? total : 0u;
        __syncthreads();
        for (int d = 1; d < 256; d <<= 1) {
            unsigned int u2 = (t >= d) ? sc[t - d] : 0u;
            __syncthreads();
            sc[t] += u2;
            __syncthreads();
        }
        const unsigned int base = sc[t] - ((t < nbuck) ? total : 0u);
        if (t < nbuck) {
            cur[t] = base + mine;
            if (blk == 0) {
                bbase[t] = base;
                totals[t] = total;
            }
        }
        __syncthreads();
        const int s = blk * chunk;
        const int e = min(s + chunk, E);
        const int n4 = (e - s) >> 2;
        const uint4* ec4 = (const uint4*)(ecol + s);
        const uint4* er4 = (const uint4*)(erow + s);
        for (int i = t; i < n4; i += 256) {
            uint4 d = ec4[i];
            uint4 r = er4[i];
            unsigned int p;
            p = atomicAdd(&cur[d.x >> 9], 1u); packed[p] = (r.x << 9) | (d.x & 511u);
            p = atomicAdd(&cur[d.y >> 9], 1u); packed[p] = (r.y << 9) | (d.y & 511u);
            p = atomicAdd(&cur[d.z >> 9], 1u); packed[p] = (r.z << 9) | (d.z & 511u);
            p = atomicAdd(&cur[d.w >> 9], 1u); packed[p] = (r.w << 9) | (d.w & 511u);
        }
        for (int i = s + (n4 << 2) + t; i < e; i += 256) {
            unsigned int d = (unsigned int)ecol[i];
            unsigned int p = atomicAdd(&cur[d >> 9], 1u);
            packed[p] = (((unsigned int)erow[i]) << 9) | (d & 511u);
        }
    }
    gsync(bar);

    // ---------------- phase 3: fine sort (2 bins/thread) ----------------
    if (blk < nbuck) {
        unsigned int* fh = (unsigned int*)smem;  // [512]
        unsigned int* sc = fh + 512;             // [256]
        const unsigned int ebase = bbase[blk];
        const unsigned int ecnt = totals[blk];
        fh[t] = 0u;
        fh[t + 256] = 0u;
        __syncthreads();
        for (unsigned int j = t; j < ecnt; j += 256)
            atomicAdd(&fh[packed[ebase + j] & 511u], 1u);
        __syncthreads();
        const unsigned int v0 = fh[2 * t], v1 = fh[2 * t + 1];
        const unsigned int pair = v0 + v1;
        sc[t] = pair;
        __syncthreads();
        for (int d = 1; d < 256; d <<= 1) {
            unsigned int u2 = (t >= d) ? sc[t - d] : 0u;
            __syncthreads();
            sc[t] += u2;
            __syncthreads();
        }
        const unsigned int pexcl = sc[t] - pair;
        const int node0 = (blk << 9) + 2 * t;
        if (node0 < N) {
            meta[node0] = make_uint2(ebase + pexcl, v0);
            dinv[node0] = rsqrtf((float)v0 + 1.0f);
        }
        if (node0 + 1 < N) {
            meta[node0 + 1] = make_uint2(ebase + pexcl + v0, v1);
            dinv[node0 + 1] = rsqrtf((float)v1 + 1.0f);
        }
        __syncthreads();
        fh[2 * t] = pexcl;  // cursors
        fh[2 * t + 1] = pexcl + v0;
        __syncthreads();
        for (unsigned int j = t; j < ecnt; j += 256) {
            unsigned int p = packed[ebase + j];
            unsigned int pos = atomicAdd(&fh[p & 511u], 1u);
            srcs[ebase + pos] = (p >> 9) << 7;  // byte offset of source row
        }
    }
    gsync(bar);

    // ---------------- phase 4: gemm1 (x f32 @ W1 -> G16) ----------------
    {
        const int lane = t & 63;
        const int col = lane & 15;
        const int kg = lane >> 4;
        bf16x8 wf[4][2];
#pragma unroll
        for (int tt = 0; tt < 4; ++tt)
#pragma unroll
            for (int s = 0; s < 2; ++s)
#pragma unroll
                for (int e = 0; e < 8; ++e)
                    wf[tt][s][e] =
                        (short)(f2bf_r(W1[(s * 32 + kg * 8 + e) * 64 + tt * 16 + col]) >> 16);
        const int wid = blk * 4 + (t >> 6);
        const int nrb = (N + 15) >> 4;
        for (int rb = wid; rb < nrb; rb += NB_GRID * 4) {
            const int arow = min(rb * 16 + col, N - 1);
            bf16x8 af0, af1;
            const float4* p = (const float4*)(x + (size_t)arow * 64 + kg * 8);
            float4 q0 = p[0], q1 = p[1], q2 = p[8], q3 = p[9];
            af0[0] = (short)(f2bf_r(q0.x) >> 16); af0[1] = (short)(f2bf_r(q0.y) >> 16);
            af0[2] = (short)(f2bf_r(q0.z) >> 16); af0[3] = (short)(f2bf_r(q0.w) >> 16);
            af0[4] = (short)(f2bf_r(q1.x) >> 16); af0[5] = (short)(f2bf_r(q1.y) >> 16);
            af0[6] = (short)(f2bf_r(q1.z) >> 16); af0[7] = (short)(f2bf_r(q1.w) >> 16);
            af1[0] = (short)(f2bf_r(q2.x) >> 16); af1[1] = (short)(f2bf_r(q2.y) >> 16);
            af1[2] = (short)(f2bf_r(q2.z) >> 16); af1[3] = (short)(f2bf_r(q2.w) >> 16);
            af1[4] = (short)(f2bf_r(q3.x) >> 16); af1[5] = (short)(f2bf_r(q3.y) >> 16);
            af1[6] = (short)(f2bf_r(q3.z) >> 16); af1[7] = (short)(f2bf_r(q3.w) >> 16);
            f32x4 zero = {0.0f, 0.0f, 0.0f, 0.0f};
            f32x4 acc0 = zero, acc1 = zero, acc2 = zero, acc3 = zero;
            acc0 = __builtin_amdgcn_mfma_f32_16x16x32_bf16(af0, wf[0][0], acc0, 0, 0, 0);
            acc1 = __builtin_amdgcn_mfma_f32_16x16x32_bf16(af0, wf[1][0], acc1, 0, 0, 0);
            acc2 = __builtin_amdgcn_mfma_f32_16x16x32_bf16(af0, wf[2][0], acc2, 0, 0, 0);
            acc3 = __builtin_amdgcn_mfma_f32_16x16x32_bf16(af0, wf[3][0], acc3, 0, 0, 0);
            acc0 = __builtin_amdgcn_mfma_f32_16x16x32_bf16(af1, wf[0][1], acc0, 0, 0, 0);
            acc1 = __builtin_amdgcn_mfma_f32_16x16x32_bf16(af1, wf[1][1], acc1, 0, 0, 0);
            acc2 = __builtin_amdgcn_mfma_f32_16x16x32_bf16(af1, wf[2][1], acc2, 0, 0, 0);
            acc3 = __builtin_amdgcn_mfma_f32_16x16x32_bf16(af1, wf[3][1], acc3, 0, 0, 0);
#pragma unroll
            for (int reg = 0; reg < 4; ++reg) {
                const int r = rb * 16 + kg * 4 + reg;
                if (r < N) {
                    const float dv = dinv[r];
                    unsigned short* gp = G16 + (size_t)r * 64 + col;
                    gp[0]  = (unsigned short)(f2bf_r(acc0[reg] * dv) >> 16);
                    gp[16] = (unsigned short)(f2bf_r(acc1[reg] * dv) >> 16);
                    gp[32] = (unsigned short)(f2bf_r(acc2[reg] * dv) >> 16);
                    gp[48] = (unsigned short)(f2bf_r(acc3[reg] * dv) >> 16);
                }
            }
        }
    }
    gsync(bar);

    // ---------------- phase 5: agg layer1 + gemm2 (fused) ----------------
    {
        unsigned int* slds = (unsigned int*)smem;       // [768]
        uint4* hlds4 = (uint4*)(smem + 3072);           // 32x64 bf16 = 256 uint4
        const int lane = t & 63;
        const int grp = lane >> 3;
        const int sub = lane & 7;
        const int wid = t >> 6;
        const int rowhalf = wid >> 1;
        const int colpair = wid & 1;
        const int mcol = lane & 15;
        const int kg = lane >> 4;
        bf16x8 wf[2][2];
#pragma unroll
        for (int ct = 0; ct < 2; ++ct)
#pragma unroll
            for (int s = 0; s < 2; ++s)
#pragma unroll
                for (int e = 0; e < 8; ++e)
                    wf[ct][s][e] = (short)(f2bf_r(W2[(s * 32 + kg * 8 + e) * 64 +
                                                     colpair * 32 + ct * 16 + mcol]) >> 16);
        const char* Gb = (const char*)G16;
        const int ntile = (N + 31) / 32;
        for (int tile = blk; tile < ntile; tile += NB_GRID) {
            const int nodeBase = tile * 32;
            hlds4[t] = make_uint4(0u, 0u, 0u, 0u);
            const int nLast = min(nodeBase + 31, N - 1);
            const unsigned int base = meta[nodeBase].x;
            const uint2 lastm = meta[nLast];
            const unsigned int blen = lastm.x + lastm.y - base;
            for (unsigned int i = t; i < blen && i < SCAP; i += 256)
                slds[i] = srcs[base + i];
            __syncthreads();
            const int node = nodeBase + wid * 8 + grp;
            if (node < N) {
                const uint2 oc = meta[node];
                const unsigned int orel = oc.x - base;
                const unsigned int c = oc.y;
                const unsigned int suboff = (unsigned int)sub << 4;
#define LDSRC(i) ((i) < SCAP ? slds[i] : srcs[base + (i)])
                float a0 = 0.f, a1 = 0.f, a2 = 0.f, a3 = 0.f;
                float a4 = 0.f, a5 = 0.f, a6 = 0.f, a7 = 0.f;
#define ACCUM(v)                              \
    do {                                      \
        a0 += bflo((v).x); a1 += bfhi((v).x); \
        a2 += bflo((v).y); a3 += bfhi((v).y); \
        a4 += bflo((v).z); a5 += bfhi((v).z); \
        a6 += bflo((v).w); a7 += bfhi((v).w); \
    } while (0)
                unsigned int j = 0;
                for (; j + 4 <= c; j += 4) {
                    unsigned int s0 = LDSRC(orel + j);
                    unsigned int s1 = LDSRC(orel + j + 1);
                    unsigned int s2 = LDSRC(orel + j + 2);
                    unsigned int s3 = LDSRC(orel + j + 3);
                    uint4 v0 = *(const uint4*)(Gb + (s0 | suboff));
                    uint4 v1 = *(const uint4*)(Gb + (s1 | suboff));
                    uint4 v2 = *(const uint4*)(Gb + (s2 | suboff));
                    uint4 v3 = *(const uint4*)(Gb + (s3 | suboff));
                    ACCUM(v0); ACCUM(v1); ACCUM(v2); ACCUM(v3);
                }
                for (; j < c; ++j) {
                    unsigned int s0 = LDSRC(orel + j);
                    uint4 v = *(const uint4*)(Gb + (s0 | suboff));
                    ACCUM(v);
                }
                {
                    uint4 g = *(const uint4*)(Gb + (((unsigned int)node << 7) | suboff));
                    ACCUM(g);
                }
                const float dv = dinv[node];
                const float4 b0 = ((const float4*)b1)[sub * 2];
                const float4 bb1 = ((const float4*)b1)[sub * 2 + 1];
                float o0 = fmaxf(fmaf(a0, dv, b0.x), 0.0f);
                float o1 = fmaxf(fmaf(a1, dv, b0.y), 0.0f);
                float o2 = fmaxf(fmaf(a2, dv, b0.z), 0.0f);
                float o3 = fmaxf(fmaf(a3, dv, b0.w), 0.0f);
                float o4 = fmaxf(fmaf(a4, dv, bb1.x), 0.0f);
                float o5 = fmaxf(fmaf(a5, dv, bb1.y), 0.0f);
                float o6 = fmaxf(fmaf(a6, dv, bb1.z), 0.0f);
                float o7 = fmaxf(fmaf(a7, dv, bb1.w), 0.0f);
                uint4 outv;
                outv.x = (f2bf_r(o0) >> 16) | (f2bf_r(o1) & 0xFFFF0000u);
                outv.y = (f2bf_r(o2) >> 16) | (f2bf_r(o3) & 0xFFFF0000u);
                outv.z = (f2bf_r(o4) >> 16) | (f2bf_r(o5) & 0xFFFF0000u);
                outv.w = (f2bf_r(o6) >> 16) | (f2bf_r(o7) & 0xFFFF0000u);
                const int row = node - nodeBase;
                hlds4[(row << 3) | (sub ^ (row & 7))] = outv;  // swizzled
            }
            __syncthreads();
            const int arow = rowhalf * 16 + mcol;
            const int slot0 = kg ^ (arow & 7);
            bf16x8 af0 = *(const bf16x8*)&hlds4[(arow << 3) | slot0];
            bf16x8 af1 = *(const bf16x8*)&hlds4[(arow << 3) | (slot0 ^ 4)];
            f32x4 zero = {0.0f, 0.0f, 0.0f, 0.0f};
            f32x4 acc0 = zero, acc1 = zero;
            acc0 = __builtin_amdgcn_mfma_f32_16x16x32_bf16(af0, wf[0][0], acc0, 0, 0, 0);
            acc1 = __builtin_amdgcn_mfma_f32_16x16x32_bf16(af0, wf[1][0], acc1, 0, 0, 0);
            acc0 = __builtin_amdgcn_mfma_f32_16x16x32_bf16(af1, wf[0][1], acc0, 0, 0, 0);
            acc1 = __builtin_amdgcn_mfma_f32_16x16x32_bf16(af1, wf[1][1], acc1, 0, 0, 0);
#pragma unroll
            for (int reg = 0; reg < 4; ++reg) {
                const int r = nodeBase + rowhalf * 16 + kg * 4 + reg;
                if (r < N) {
                    const float dv = dinv[r];
                    unsigned short* gp = G2 + (size_t)r * 64 + colpair * 32 + mcol;
                    gp[0]  = (unsigned short)(f2bf_r(acc0[reg] * dv) >> 16);
                    gp[16] = (unsigned short)(f2bf_r(acc1[reg] * dv) >> 16);
                }
            }
            __syncthreads();
        }
    }
    gsync(bar);

    // ---------------- phase 6: agg layer2 -> H16 ----------------
    {
        unsigned int* slds = (unsigned int*)smem;
        const int lane = t & 63;
        const int grp = lane >> 3;
        const int sub = lane & 7;
        const int wid = t >> 6;
        const char* Gb = (const char*)G2;
        uint4* H4 = (uint4*)H16;
        const int ntile = (N + 31) / 32;
        for (int tile = blk; tile < ntile; tile += NB_GRID) {
            const int nodeBase = tile * 32;
            const int nLast = min(nodeBase + 31, N - 1);
            const unsigned int base = meta[nodeBase].x;
            const uint2 lastm = meta[nLast];
            const unsigned int blen = lastm.x + lastm.y - base;
            for (unsigned int i = t; i < blen && i < SCAP; i += 256)
                slds[i] = srcs[base + i];
            __syncthreads();
            const int node = nodeBase + wid * 8 + grp;
            if (node < N) {
                const uint2 oc = meta[node];
                const unsigned int orel = oc.x - base;
                const unsigned int c = oc.y;
                const unsigned int suboff = (unsigned int)sub << 4;
                float a0 = 0.f, a1 = 0.f, a2 = 0.f, a3 = 0.f;
                float a4 = 0.f, a5 = 0.f, a6 = 0.f, a7 = 0.f;
                unsigned int j = 0;
                for (; j + 4 <= c; j += 4) {
                    unsigned int s0 = LDSRC(orel + j);
                    unsigned int s1 = LDSRC(orel + j + 1);
                    unsigned int s2 = LDSRC(orel + j + 2);
                    unsigned int s3 = LDSRC(orel + j + 3);
                    uint4 v0 = *(const uint4*)(Gb + (s0 | suboff));
                    uint4 v1 = *(const uint4*)(Gb + (s1 | suboff));
                    uint4 v2 = *(const uint4*)(Gb + (s2 | suboff));
                    uint4 v3 = *(const uint4*)(Gb + (s3 | suboff));
                    ACCUM(v0); ACCUM(v1); ACCUM(v2); ACCUM(v3);
                }
                for (; j < c; ++j) {
                    unsigned int s0 = LDSRC(orel + j);
                    uint4 v = *(const uint4*)(Gb + (s0 | suboff));
                    ACCUM(v);
                }
                {
                    uint4 g = *(const uint4*)(Gb + (((unsigned int)node << 7) | suboff));
                    ACCUM(g);
                }
#undef ACCUM
#undef LDSRC
                const float dv = dinv[node];
                const float4 c0 = ((const float4*)b2)[sub * 2];
                const float4 c1 = ((const float4*)b2)[sub * 2 + 1];
                float o0 = fmaxf(fmaf(a0, dv, c0.x), 0.0f);
                float o1 = fmaxf(fmaf(a1, dv, c0.y), 0.0f);
                float o2 = fmaxf(fmaf(a2, dv, c0.z), 0.0f);
                float o3 = fmaxf(fmaf(a3, dv, c0.w), 0.0f);
                float o4 = fmaxf(fmaf(a4, dv, c1.x), 0.0f);
                float o5 = fmaxf(fmaf(a5, dv, c1.y), 0.0f);
                float o6 = fmaxf(fmaf(a6, dv, c1.z), 0.0f);
                float o7 = fmaxf(fmaf(a7, dv, c1.w), 0.0f);
                uint4 outv;
                outv.x = (f2bf_r(o0) >> 16) | (f2bf_r(o1) & 0xFFFF0000u);
                outv.y = (f2bf_r(o2) >> 16) | (f2bf_r(o3) & 0xFFFF0000u);
                outv.z = (f2bf_r(o4) >> 16) | (f2bf_r(o5) & 0xFFFF0000u);
                outv.w = (f2bf_r(o6) >> 16) | (f2bf_r(o7) & 0xFFFF0000u);
                H4[(size_t)node * 8 + sub] = outv;
            }
            __syncthreads();
        }
    }
    gsync(bar);

    // ---------------- phase 7: mean pool + FC ----------------
    if (blk < Gn) {
        float* sh = (float*)smem;       // [512]
        float* p = sh + 512;            // [64]
        const unsigned int* H2 = (const unsigned int*)H16;
        const int g = blk;
        int lo = 0, hi = N;
        while (lo < hi) {
            int mid = (lo + hi) >> 1;
            if (batch[mid] < g) lo = mid + 1; else hi = mid;
        }
        const int start = lo;
        hi = N;
        while (lo < hi) {
            int mid = (lo + hi) >> 1;
            if (batch[mid] < g + 1) lo = mid + 1; else hi = mid;
        }
        const int end = lo;
        const int w = t >> 5;
        const int c = t & 31;
        float acc0 = 0.f, acc1 = 0.f;
        for (int i = start + w; i < end; i += 8) {
            unsigned int v = H2[(size_t)i * 32 + c];
            acc0 += bflo(v);
            acc1 += bfhi(v);
        }
        sh[w * 64 + 2 * c] = acc0;
        sh[w * 64 + 2 * c + 1] = acc1;
        __syncthreads();
        if (t < 64) {
            float s = 0.f;
#pragma unroll
            for (int i = 0; i < 8; ++i) s += sh[i * 64 + t];
            p[t] = s / (float)max(end - start, 1);
        }
        __syncthreads();
        if (t < 10) {
            float a = bfc[t];
#pragma unroll
            for (int k = 0; k < 64; ++k) a = fmaf(p[k], Wfc[k * 10 + t], a);
            out[g * 10 + t] = a;
        }
    }
}

extern "C" void kernel_launch(void* const* d_in, const int* in_sizes, int n_in,
                              void* d_out, int out_size, void* d_ws, size_t ws_size,
                              hipStream_t stream) {
    const float* x     = (const float*)d_in[0];
    const float* W1    = (const float*)d_in[1];
    const float* b1    = (const float*)d_in[2];
    const float* W2    = (const float*)d_in[3];
    const float* b2    = (const float*)d_in[4];
    const float* Wfc   = (const float*)d_in[5];
    const float* bfc   = (const float*)d_in[6];
    const int*   eidx  = (const int*)d_in[7];
    const int*   batch = (const int*)d_in[8];

    const int N = in_sizes[0] / 64;
    const int E = in_sizes[7] / 2;
    const int Gn = out_size / 10;
    const int* erow = eidx;      // sources
    const int* ecol = eidx + E;  // destinations

    const int nbuck = (N + 511) >> 9;  // coarse buckets (<= 256)
    const int chunk = (((E + NSORT - 1) / NSORT) + 3) & ~3;

    char* ws = (char*)d_ws;
    size_t off = 0;
    auto alloc = [&](size_t bytes) -> void* {
        void* p = ws + off;
        off = (off + bytes + 511) & ~(size_t)511;
        return p;
    };
    uint2*        meta   = (uint2*)alloc((size_t)N * 8);
    float*        dinv   = (float*)alloc((size_t)N * 4);
    unsigned int* totals = (unsigned int*)alloc((size_t)nbuck * 4);
    unsigned int* bbase  = (unsigned int*)alloc((size_t)nbuck * 4);
    unsigned int* srcs   = (unsigned int*)alloc((size_t)E * 4);
    unsigned short* G16  = (unsigned short*)alloc((size_t)N * 64 * 2);
    unsigned short* G2   = (unsigned short*)alloc((size_t)N * 64 * 2);
    unsigned short* H16  = (unsigned short*)alloc((size_t)N * 64 * 2);
    unsigned int* bhist  = (unsigned int*)alloc((size_t)NSORT * 256 * 4);
    unsigned int* bar    = (unsigned int*)alloc(64);

    // packed aliases H16 (dead before H16 is first written in phase 6)
    unsigned int* packed = (unsigned int*)H16;

    init_k<<<1, 64, 0, stream>>>(bar);
    mega_k<<<NB_GRID, 256, 0, stream>>>(erow, ecol, x, W1, b1, W2, b2, Wfc, bfc,
                                        batch, bhist, bbase, totals, packed,
                                        meta, dinv, srcs, G16, G2, H16,
                                        (float*)d_out, bar, N, E, Gn, nbuck,
                                        chunk);
}

// Round 10
// 106.845 us; speedup vs baseline: 24.1778x; 24.1778x over previous
//
#include <hip/hip_runtime.h>
#include <cstdint>

// ---------------------------------------------------------------------------
// GCN forward: 2x (GEMM 64x64 -> symmetric-norm edge aggregation -> bias+ReLU)
// then global mean pool (sorted batch) and 64x10 FC.
//
// 6 dispatches (R9 lesson: software grid barriers cost ~100x a dispatch
// boundary on 8-XCD MI355X; block-local fusion is the way):
//   hist_k     : per-block LDS histogram of coarse bucket (dst>>9) + zero pooled
//   scatter2_k : fused per-block scan of bhist -> scatter packed edges
//   finegemm_k : per-bucket 512-bin sort -> srcs CSR (byte offs), meta, dinv
//                THEN gemm1 (MFMA) for the bucket's own 512 rows (dinv in LDS)
//   agg_gemm_k : agg layer1 (gather) -> H tile in LDS (swizzled) -> MFMA @ W2
//   agg_pool_k : agg layer2 -> H rows in LDS -> per-graph partial sums
//                -> atomicAdd into pooled   [H never hits global memory]
//   fc_k       : pooled/count (binary search on sorted batch) @ Wfc + bfc
// ---------------------------------------------------------------------------

#define NSORT 256
#define SCAP 768  // LDS srcs window entries per agg tile (32 nodes, ~384 avg)

typedef __attribute__((ext_vector_type(8))) short bf16x8;
typedef __attribute__((ext_vector_type(4))) float f32x4;

static __device__ __forceinline__ unsigned int f2bf_r(float f) {
    unsigned int u = __float_as_uint(f);
    return u + 0x7FFFu + ((u >> 16) & 1u);  // rounded, needs >>16
}
static __device__ __forceinline__ float bflo(unsigned int v) {
    return __uint_as_float(v << 16);
}
static __device__ __forceinline__ float bfhi(unsigned int v) {
    return __uint_as_float(v & 0xFFFF0000u);
}

__global__ __launch_bounds__(256) void hist_k(const int* __restrict__ ecol,
                                              unsigned int* __restrict__ bhist,
                                              float* __restrict__ pooled_zero, int zn,
                                              int E, int chunk, int nbuck) {
    __shared__ unsigned int lh[256];
    lh[threadIdx.x] = 0u;
    __syncthreads();
    if (blockIdx.x == 0) {
        for (int i = threadIdx.x; i < zn; i += 256) pooled_zero[i] = 0.f;
    }
    const int s = blockIdx.x * chunk;
    const int e = min(s + chunk, E);
    const int n4 = (e - s) >> 2;
    const uint4* ec4 = (const uint4*)(ecol + s);
    for (int i = threadIdx.x; i < n4; i += 256) {
        uint4 v = ec4[i];
        atomicAdd(&lh[v.x >> 9], 1u);
        atomicAdd(&lh[v.y >> 9], 1u);
        atomicAdd(&lh[v.z >> 9], 1u);
        atomicAdd(&lh[v.w >> 9], 1u);
    }
    for (int i = s + (n4 << 2) + threadIdx.x; i < e; i += 256)
        atomicAdd(&lh[((unsigned int)ecol[i]) >> 9], 1u);
    __syncthreads();
    if ((int)threadIdx.x < nbuck)
        bhist[threadIdx.x * NSORT + blockIdx.x] = lh[threadIdx.x];
}

// scatter with fused scan: each block recomputes bucket totals + its own
// prefix from bhist ([bucket][block] layout); block 0 publishes bbase/totals.
__global__ __launch_bounds__(256) void scatter2_k(const int* __restrict__ erow,
                                                  const int* __restrict__ ecol,
                                                  const unsigned int* __restrict__ bhist,
                                                  unsigned int* __restrict__ bbase_out,
                                                  unsigned int* __restrict__ totals_out,
                                                  unsigned int* __restrict__ packed,
                                                  int E, int chunk, int nbuck) {
    __shared__ unsigned int cur[256];
    __shared__ unsigned int sc[256];
    const int t = threadIdx.x;
    const int blk = blockIdx.x;
    unsigned int total = 0u, mine = 0u;
    if (t < nbuck) {
        const uint4* h4 = (const uint4*)(bhist + t * NSORT);
#pragma unroll 8
        for (int i = 0; i < NSORT / 4; ++i) {
            uint4 v = h4[i];
            const int b0 = i * 4;
            total += v.x + v.y + v.z + v.w;
            mine += (b0 + 0 < blk ? v.x : 0u) + (b0 + 1 < blk ? v.y : 0u) +
                    (b0 + 2 < blk ? v.z : 0u) + (b0 + 3 < blk ? v.w : 0u);
        }
    }
    sc[t] = (t < nbuck) ? total : 0u;
    __syncthreads();
    for (int d = 1; d < 256; d <<= 1) {
        unsigned int u2 = (t >= d) ? sc[t - d] : 0u;
        __syncthreads();
        sc[t] += u2;
        __syncthreads();
    }
    const unsigned int base = sc[t] - ((t < nbuck) ? total : 0u);
    if (t < nbuck) {
        cur[t] = base + mine;
        if (blk == 0) {
            bbase_out[t] = base;
            totals_out[t] = total;
        }
    }
    __syncthreads();
    const int s = blk * chunk;
    const int e = min(s + chunk, E);
    const int n4 = (e - s) >> 2;
    const uint4* ec4 = (const uint4*)(ecol + s);
    const uint4* er4 = (const uint4*)(erow + s);
    for (int i = t; i < n4; i += 256) {
        uint4 d = ec4[i];
        uint4 r = er4[i];
        unsigned int p;
        p = atomicAdd(&cur[d.x >> 9], 1u); packed[p] = (r.x << 9) | (d.x & 511u);
        p = atomicAdd(&cur[d.y >> 9], 1u); packed[p] = (r.y << 9) | (d.y & 511u);
        p = atomicAdd(&cur[d.z >> 9], 1u); packed[p] = (r.z << 9) | (d.z & 511u);
        p = atomicAdd(&cur[d.w >> 9], 1u); packed[p] = (r.w << 9) | (d.w & 511u);
    }
    for (int i = s + (n4 << 2) + t; i < e; i += 256) {
        unsigned int d = (unsigned int)ecol[i];
        unsigned int p = atomicAdd(&cur[d >> 9], 1u);
        packed[p] = (((unsigned int)erow[i]) << 9) | (d & 511u);
    }
}

// one block (512 thr) per bucket: fine sort -> srcs/meta/dinv, then gemm1 for
// the bucket's own 512 rows (dinv held in LDS -> no cross-block dependency).
__global__ __launch_bounds__(512) void finegemm_k(const unsigned int* __restrict__ packed,
                                                  const unsigned int* __restrict__ bbase,
                                                  const unsigned int* __restrict__ totals,
                                                  uint2* __restrict__ meta,
                                                  float* __restrict__ dinv,
                                                  unsigned int* __restrict__ srcs,
                                                  const float* __restrict__ x,
                                                  const float* __restrict__ W1,
                                                  unsigned short* __restrict__ G16,
                                                  int N) {
    __shared__ unsigned int fh[512];
    __shared__ unsigned int sc[512];
    __shared__ float dld[512];
    const int k = blockIdx.x;
    const int t = threadIdx.x;
    const unsigned int ebase = bbase[k];
    const unsigned int ecnt = totals[k];
    fh[t] = 0u;
    __syncthreads();
    for (unsigned int j = t; j < ecnt; j += 512)
        atomicAdd(&fh[packed[ebase + j] & 511u], 1u);
    __syncthreads();
    unsigned int v = fh[t];
    sc[t] = v;
    __syncthreads();
    for (int d = 1; d < 512; d <<= 1) {
        unsigned int u2 = (t >= d) ? sc[t - d] : 0u;
        __syncthreads();
        sc[t] += u2;
        __syncthreads();
    }
    const unsigned int excl = sc[t] - v;
    const int node = (k << 9) + t;
    const float dv_t = rsqrtf((float)v + 1.0f);  // +1 self loop
    dld[t] = dv_t;
    if (node < N) {
        meta[node] = make_uint2(ebase + excl, v);
        dinv[node] = dv_t;
    }
    __syncthreads();
    fh[t] = excl;  // reuse as cursor
    __syncthreads();
    for (unsigned int j = t; j < ecnt; j += 512) {
        unsigned int p = packed[ebase + j];
        unsigned int pos = atomicAdd(&fh[p & 511u], 1u);
        srcs[ebase + pos] = (p >> 9) << 7;  // byte offset of source row
    }
    // ---- gemm1 for rows [k*512, k*512+512) ----
    const int lane = t & 63;
    const int wave = t >> 6;  // 0..7
    const int col = lane & 15;
    const int kg = lane >> 4;
    bf16x8 wf[4][2];
#pragma unroll
    for (int tt = 0; tt < 4; ++tt)
#pragma unroll
        for (int s = 0; s < 2; ++s)
#pragma unroll
            for (int e = 0; e < 8; ++e)
                wf[tt][s][e] =
                    (short)(f2bf_r(W1[(s * 32 + kg * 8 + e) * 64 + tt * 16 + col]) >> 16);
    const int rbase = k << 9;
#pragma unroll
    for (int tile = wave; tile < 32; tile += 8) {
        const int r0 = rbase + tile * 16;
        if (r0 >= N) break;
        const int arow = min(r0 + col, N - 1);
        bf16x8 af0, af1;
        const float4* p = (const float4*)(x + (size_t)arow * 64 + kg * 8);
        float4 q0 = p[0], q1 = p[1], q2 = p[8], q3 = p[9];
        af0[0] = (short)(f2bf_r(q0.x) >> 16); af0[1] = (short)(f2bf_r(q0.y) >> 16);
        af0[2] = (short)(f2bf_r(q0.z) >> 16); af0[3] = (short)(f2bf_r(q0.w) >> 16);
        af0[4] = (short)(f2bf_r(q1.x) >> 16); af0[5] = (short)(f2bf_r(q1.y) >> 16);
        af0[6] = (short)(f2bf_r(q1.z) >> 16); af0[7] = (short)(f2bf_r(q1.w) >> 16);
        af1[0] = (short)(f2bf_r(q2.x) >> 16); af1[1] = (short)(f2bf_r(q2.y) >> 16);
        af1[2] = (short)(f2bf_r(q2.z) >> 16); af1[3] = (short)(f2bf_r(q2.w) >> 16);
        af1[4] = (short)(f2bf_r(q3.x) >> 16); af1[5] = (short)(f2bf_r(q3.y) >> 16);
        af1[6] = (short)(f2bf_r(q3.z) >> 16); af1[7] = (short)(f2bf_r(q3.w) >> 16);
        f32x4 zero = {0.0f, 0.0f, 0.0f, 0.0f};
        f32x4 acc0 = zero, acc1 = zero, acc2 = zero, acc3 = zero;
        acc0 = __builtin_amdgcn_mfma_f32_16x16x32_bf16(af0, wf[0][0], acc0, 0, 0, 0);
        acc1 = __builtin_amdgcn_mfma_f32_16x16x32_bf16(af0, wf[1][0], acc1, 0, 0, 0);
        acc2 = __builtin_amdgcn_mfma_f32_16x16x32_bf16(af0, wf[2][0], acc2, 0, 0, 0);
        acc3 = __builtin_amdgcn_mfma_f32_16x16x32_bf16(af0, wf[3][0], acc3, 0, 0, 0);
        acc0 = __builtin_amdgcn_mfma_f32_16x16x32_bf16(af1, wf[0][1], acc0, 0, 0, 0);
        acc1 = __builtin_amdgcn_mfma_f32_16x16x32_bf16(af1, wf[1][1], acc1, 0, 0, 0);
        acc2 = __builtin_amdgcn_mfma_f32_16x16x32_bf16(af1, wf[2][1], acc2, 0, 0, 0);
        acc3 = __builtin_amdgcn_mfma_f32_16x16x32_bf16(af1, wf[3][1], acc3, 0, 0, 0);
#pragma unroll
        for (int reg = 0; reg < 4; ++reg) {
            const int r = r0 + kg * 4 + reg;
            if (r < N) {
                const float dv = dld[r - rbase];
                unsigned short* gp = G16 + (size_t)r * 64 + col;
                gp[0]  = (unsigned short)(f2bf_r(acc0[reg] * dv) >> 16);
                gp[16] = (unsigned short)(f2bf_r(acc1[reg] * dv) >> 16);
                gp[32] = (unsigned short)(f2bf_r(acc2[reg] * dv) >> 16);
                gp[48] = (unsigned short)(f2bf_r(acc3[reg] * dv) >> 16);
            }
        }
    }
}

// Fused layer-1 agg + layer-2 GEMM. Block = 32 nodes.
__global__ __launch_bounds__(256) void agg_gemm_k(const char* __restrict__ Gb,
                                                  const uint2* __restrict__ meta,
                                                  const unsigned int* __restrict__ srcs,
                                                  const float* __restrict__ dinv,
                                                  const float* __restrict__ bias,
                                                  const float* __restrict__ W2,
                                                  unsigned short* __restrict__ G2,
                                                  int N) {
    __shared__ unsigned int slds[SCAP];
    __shared__ unsigned short hlds[32 * 64];
    uint4* hlds4 = (uint4*)hlds;
    hlds4[threadIdx.x] = make_uint4(0u, 0u, 0u, 0u);

    const int nodeBase = blockIdx.x * 32;
    const int nLast = min(nodeBase + 31, N - 1);
    const unsigned int base = meta[nodeBase].x;
    const uint2 lastm = meta[nLast];
    const unsigned int blen = lastm.x + lastm.y - base;
    for (unsigned int i = threadIdx.x; i < blen && i < SCAP; i += 256)
        slds[i] = srcs[base + i];
    __syncthreads();

    const int lane = threadIdx.x & 63;
    const int grp = lane >> 3;
    const int sub = lane & 7;
    const int node = nodeBase + (threadIdx.x >> 6) * 8 + grp;
    if (node < N) {
        const uint2 oc = meta[node];
        const unsigned int orel = oc.x - base;
        const unsigned int c = oc.y;
        const unsigned int suboff = (unsigned int)sub << 4;
#define LDSRC(i) ((i) < SCAP ? slds[i] : srcs[base + (i)])
        float a0 = 0.f, a1 = 0.f, a2 = 0.f, a3 = 0.f;
        float a4 = 0.f, a5 = 0.f, a6 = 0.f, a7 = 0.f;
#define ACCUM(v)                              \
    do {                                      \
        a0 += bflo((v).x); a1 += bfhi((v).x); \
        a2 += bflo((v).y); a3 += bfhi((v).y); \
        a4 += bflo((v).z); a5 += bfhi((v).z); \
        a6 += bflo((v).w); a7 += bfhi((v).w); \
    } while (0)
        unsigned int j = 0;
        for (; j + 4 <= c; j += 4) {
            unsigned int s0 = LDSRC(orel + j);
            unsigned int s1 = LDSRC(orel + j + 1);
            unsigned int s2 = LDSRC(orel + j + 2);
            unsigned int s3 = LDSRC(orel + j + 3);
            uint4 v0 = *(const uint4*)(Gb + (s0 | suboff));
            uint4 v1 = *(const uint4*)(Gb + (s1 | suboff));
            uint4 v2 = *(const uint4*)(Gb + (s2 | suboff));
            uint4 v3 = *(const uint4*)(Gb + (s3 | suboff));
            ACCUM(v0); ACCUM(v1); ACCUM(v2); ACCUM(v3);
        }
        for (; j < c; ++j) {
            unsigned int s0 = LDSRC(orel + j);
            uint4 v = *(const uint4*)(Gb + (s0 | suboff));
            ACCUM(v);
        }
        {
            uint4 g = *(const uint4*)(Gb + (((unsigned int)node << 7) | suboff));
            ACCUM(g);
        }
        const float dv = dinv[node];
        const float4 b0 = ((const float4*)bias)[sub * 2];
        const float4 b1 = ((const float4*)bias)[sub * 2 + 1];
        float o0 = fmaxf(fmaf(a0, dv, b0.x), 0.0f);
        float o1 = fmaxf(fmaf(a1, dv, b0.y), 0.0f);
        float o2 = fmaxf(fmaf(a2, dv, b0.z), 0.0f);
        float o3 = fmaxf(fmaf(a3, dv, b0.w), 0.0f);
        float o4 = fmaxf(fmaf(a4, dv, b1.x), 0.0f);
        float o5 = fmaxf(fmaf(a5, dv, b1.y), 0.0f);
        float o6 = fmaxf(fmaf(a6, dv, b1.z), 0.0f);
        float o7 = fmaxf(fmaf(a7, dv, b1.w), 0.0f);
        uint4 out;
        out.x = (f2bf_r(o0) >> 16) | (f2bf_r(o1) & 0xFFFF0000u);
        out.y = (f2bf_r(o2) >> 16) | (f2bf_r(o3) & 0xFFFF0000u);
        out.z = (f2bf_r(o4) >> 16) | (f2bf_r(o5) & 0xFFFF0000u);
        out.w = (f2bf_r(o6) >> 16) | (f2bf_r(o7) & 0xFFFF0000u);
        const int row = node - nodeBase;
        hlds4[(row << 3) | (sub ^ (row & 7))] = out;  // swizzled store
    }
    __syncthreads();

    const int wid = threadIdx.x >> 6;
    const int rowhalf = wid >> 1;
    const int colpair = wid & 1;
    const int col = lane & 15;
    const int kg = lane >> 4;
    bf16x8 wf[2][2];
#pragma unroll
    for (int ct = 0; ct < 2; ++ct)
#pragma unroll
        for (int s = 0; s < 2; ++s)
#pragma unroll
            for (int e = 0; e < 8; ++e)
                wf[ct][s][e] = (short)(f2bf_r(W2[(s * 32 + kg * 8 + e) * 64 +
                                                 colpair * 32 + ct * 16 + col]) >> 16);
    const int arow = rowhalf * 16 + col;
    const int slot0 = kg ^ (arow & 7);
    bf16x8 af0 = *(const bf16x8*)&hlds4[(arow << 3) | slot0];
    bf16x8 af1 = *(const bf16x8*)&hlds4[(arow << 3) | (slot0 ^ 4)];
    f32x4 zero = {0.0f, 0.0f, 0.0f, 0.0f};
    f32x4 acc0 = zero, acc1 = zero;
    acc0 = __builtin_amdgcn_mfma_f32_16x16x32_bf16(af0, wf[0][0], acc0, 0, 0, 0);
    acc1 = __builtin_amdgcn_mfma_f32_16x16x32_bf16(af0, wf[1][0], acc1, 0, 0, 0);
    acc0 = __builtin_amdgcn_mfma_f32_16x16x32_bf16(af1, wf[0][1], acc0, 0, 0, 0);
    acc1 = __builtin_amdgcn_mfma_f32_16x16x32_bf16(af1, wf[1][1], acc1, 0, 0, 0);
#pragma unroll
    for (int reg = 0; reg < 4; ++reg) {
        const int r = nodeBase + rowhalf * 16 + kg * 4 + reg;
        if (r < N) {
            const float dv = dinv[r];
            unsigned short* gp = G2 + (size_t)r * 64 + colpair * 32 + col;
            gp[0]  = (unsigned short)(f2bf_r(acc0[reg] * dv) >> 16);
            gp[16] = (unsigned short)(f2bf_r(acc1[reg] * dv) >> 16);
        }
    }
}

// agg layer2 + pooling: H rows stay in LDS; per-graph partial sums (batch
// sorted -> a 32-node block spans ~1-2 graphs) atomicAdd'ed into pooled.
__global__ __launch_bounds__(256) void agg_pool_k(const char* __restrict__ Gb,
                                                  const uint2* __restrict__ meta,
                                                  const unsigned int* __restrict__ srcs,
                                                  const float* __restrict__ dinv,
                                                  const float* __restrict__ bias,
                                                  const int* __restrict__ batch,
                                                  float* __restrict__ pooled, int N) {
    __shared__ unsigned int slds[SCAP];
    __shared__ unsigned int hl[32 * 32];  // 32 rows x 64ch bf16 (as uints)
    __shared__ float red[8 * 64];
    __shared__ int gb[32];
    const int t = threadIdx.x;
    const int nodeBase = blockIdx.x * 32;
    const int nLast = min(nodeBase + 31, N - 1);
    const unsigned int base = meta[nodeBase].x;
    const uint2 lastm = meta[nLast];
    const unsigned int blen = lastm.x + lastm.y - base;
    for (unsigned int i = t; i < blen && i < SCAP; i += 256)
        slds[i] = srcs[base + i];
    if (t < 32) gb[t] = (nodeBase + t < N) ? batch[nodeBase + t] : -1;
    __syncthreads();

    const int lane = t & 63;
    const int grp = lane >> 3;
    const int sub = lane & 7;
    const int node = nodeBase + (t >> 6) * 8 + grp;
    if (node < N) {
        const uint2 oc = meta[node];
        const unsigned int orel = oc.x - base;
        const unsigned int c = oc.y;
        const unsigned int suboff = (unsigned int)sub << 4;
        float a0 = 0.f, a1 = 0.f, a2 = 0.f, a3 = 0.f;
        float a4 = 0.f, a5 = 0.f, a6 = 0.f, a7 = 0.f;
        unsigned int j = 0;
        for (; j + 4 <= c; j += 4) {
            unsigned int s0 = LDSRC(orel + j);
            unsigned int s1 = LDSRC(orel + j + 1);
            unsigned int s2 = LDSRC(orel + j + 2);
            unsigned int s3 = LDSRC(orel + j + 3);
            uint4 v0 = *(const uint4*)(Gb + (s0 | suboff));
            uint4 v1 = *(const uint4*)(Gb + (s1 | suboff));
            uint4 v2 = *(const uint4*)(Gb + (s2 | suboff));
            uint4 v3 = *(const uint4*)(Gb + (s3 | suboff));
            ACCUM(v0); ACCUM(v1); ACCUM(v2); ACCUM(v3);
        }
        for (; j < c; ++j) {
            unsigned int s0 = LDSRC(orel + j);
            uint4 v = *(const uint4*)(Gb + (s0 | suboff));
            ACCUM(v);
        }
        {
            uint4 g = *(const uint4*)(Gb + (((unsigned int)node << 7) | suboff));
            ACCUM(g);
        }
#undef ACCUM
#undef LDSRC
        const float dv = dinv[node];
        const float4 c0 = ((const float4*)bias)[sub * 2];
        const float4 c1 = ((const float4*)bias)[sub * 2 + 1];
        float o0 = fmaxf(fmaf(a0, dv, c0.x), 0.0f);
        float o1 = fmaxf(fmaf(a1, dv, c0.y), 0.0f);
        float o2 = fmaxf(fmaf(a2, dv, c0.z), 0.0f);
        float o3 = fmaxf(fmaf(a3, dv, c0.w), 0.0f);
        float o4 = fmaxf(fmaf(a4, dv, c1.x), 0.0f);
        float o5 = fmaxf(fmaf(a5, dv, c1.y), 0.0f);
        float o6 = fmaxf(fmaf(a6, dv, c1.z), 0.0f);
        float o7 = fmaxf(fmaf(a7, dv, c1.w), 0.0f);
        const int row = node - nodeBase;
        unsigned int* hp = &hl[row * 32 + sub * 4];
        hp[0] = (f2bf_r(o0) >> 16) | (f2bf_r(o1) & 0xFFFF0000u);
        hp[1] = (f2bf_r(o2) >> 16) | (f2bf_r(o3) & 0xFFFF0000u);
        hp[2] = (f2bf_r(o4) >> 16) | (f2bf_r(o5) & 0xFFFF0000u);
        hp[3] = (f2bf_r(o6) >> 16) | (f2bf_r(o7) & 0xFFFF0000u);
    }
    __syncthreads();

    // pooling: per-graph partial sums
    const int g0 = gb[0];
    const int g1 = gb[nLast - nodeBase];
    const int w = t >> 5;   // 8 walkers
    const int c2 = t & 31;  // uint slot (2 channels)
    for (int g = g0; g <= g1; ++g) {
        float a0 = 0.f, a1 = 0.f;
        for (int r = w; r < 32; r += 8) {
            if (gb[r] == g) {
                unsigned int v = hl[r * 32 + c2];
                a0 += bflo(v);
                a1 += bfhi(v);
            }
        }
        red[w * 64 + 2 * c2] = a0;
        red[w * 64 + 2 * c2 + 1] = a1;
        __syncthreads();
        if (t < 64) {
            float s = 0.f;
#pragma unroll
            for (int i = 0; i < 8; ++i) s += red[i * 64 + t];
            atomicAdd(&pooled[g * 64 + t], s);
        }
        __syncthreads();
    }
}

// final FC: count per graph via binary search on sorted batch
__global__ __launch_bounds__(64) void fc_k(const float* __restrict__ pooled,
                                           const int* __restrict__ batch,
                                           const float* __restrict__ Wfc,
                                           const float* __restrict__ bfc,
                                           float* __restrict__ out, int N) {
    __shared__ float p[64];
    const int g = blockIdx.x;
    const int t = threadIdx.x;
    int lo = 0, hi = N;
    while (lo < hi) {
        int mid = (lo + hi) >> 1;
        if (batch[mid] < g) lo = mid + 1; else hi = mid;
    }
    const int start = lo;
    hi = N;
    while (lo < hi) {
        int mid = (lo + hi) >> 1;
        if (batch[mid] < g + 1) lo = mid + 1; else hi = mid;
    }
    const float cc = (float)max(lo - start, 1);
    p[t] = pooled[g * 64 + t] / cc;
    __syncthreads();
    if (t < 10) {
        float a = bfc[t];
#pragma unroll
        for (int k = 0; k < 64; ++k) a = fmaf(p[k], Wfc[k * 10 + t], a);
        out[g * 10 + t] = a;
    }
}

extern "C" void kernel_launch(void* const* d_in, const int* in_sizes, int n_in,
                              void* d_out, int out_size, void* d_ws, size_t ws_size,
                              hipStream_t stream) {
    const float* x     = (const float*)d_in[0];
    const float* W1    = (const float*)d_in[1];
    const float* b1    = (const float*)d_in[2];
    const float* W2    = (const float*)d_in[3];
    const float* b2    = (const float*)d_in[4];
    const float* Wfc   = (const float*)d_in[5];
    const float* bfc   = (const float*)d_in[6];
    const int*   eidx  = (const int*)d_in[7];
    const int*   batch = (const int*)d_in[8];

    const int N = in_sizes[0] / 64;
    const int E = in_sizes[7] / 2;
    const int Gn = out_size / 10;
    const int* erow = eidx;      // sources
    const int* ecol = eidx + E;  // destinations

    const int nbuck = (N + 511) >> 9;
    const int chunk = (((E + NSORT - 1) / NSORT) + 3) & ~3;

    char* ws = (char*)d_ws;
    size_t off = 0;
    auto alloc = [&](size_t bytes) -> void* {
        void* p = ws + off;
        off = (off + bytes + 511) & ~(size_t)511;
        return p;
    };
    uint2*        meta   = (uint2*)alloc((size_t)N * 8);
    float*        dinv   = (float*)alloc((size_t)N * 4);
    unsigned int* totals = (unsigned int*)alloc((size_t)nbuck * 4);
    unsigned int* bbase  = (unsigned int*)alloc((size_t)nbuck * 4);
    unsigned int* srcs   = (unsigned int*)alloc((size_t)E * 4);
    unsigned short* G16  = (unsigned short*)alloc((size_t)N * 64 * 2);
    unsigned short* G2   = (unsigned short*)alloc((size_t)N * 64 * 2);
    unsigned int* packed = (unsigned int*)alloc((size_t)E * 4);
    unsigned int* bhist  = (unsigned int*)alloc((size_t)NSORT * 256 * 4);
    float*        pooled = (float*)alloc((size_t)Gn * 64 * 4);

    const int ZN = Gn * 64;

    // --- CSR build + layer-1 GEMM ---
    hist_k<<<NSORT, 256, 0, stream>>>(ecol, bhist, pooled, ZN, E, chunk, nbuck);
    scatter2_k<<<NSORT, 256, 0, stream>>>(erow, ecol, bhist, bbase, totals,
                                          packed, E, chunk, nbuck);
    finegemm_k<<<nbuck, 512, 0, stream>>>(packed, bbase, totals, meta, dinv,
                                          srcs, x, W1, G16, N);

    const int aggB = (N + 31) / 32;
    // --- layer-1 agg + layer-2 GEMM ---
    agg_gemm_k<<<aggB, 256, 0, stream>>>((const char*)G16, meta, srcs, dinv, b1,
                                         W2, G2, N);
    // --- layer-2 agg + pooling ---
    agg_pool_k<<<aggB, 256, 0, stream>>>((const char*)G2, meta, srcs, dinv, b2,
                                         batch, pooled, N);
    // --- FC ---
    fc_k<<<Gn, 64, 0, stream>>>(pooled, batch, Wfc, bfc, (float*)d_out, N);
}